// Round 5
// baseline (227.990 us; speedup 1.0000x reference)
//
#include <hip/hip_runtime.h>
#include <math.h>

#define NTOT 16384
#define NSEG 2048
#define CROWS 8385ull   // 129 rows * 65 per task (chunk scans + boundary row)

// ws float offsets
#define OFF_HH   0ull         // 16384*256 (hc reuses this after head sortchunkscan)
#define OFF_XC   4194304ull   // 16384*256
#define OFF_S1H  8388608ull   // 65536
#define OFF_S2H  8454144ull   // 65536
#define OFF_S1O  8519680ull   // 16384
#define OFF_S2O  8536064ull   // 16384
#define OFF_SVAL 8552448ull   // 32*2048
#define OFF_WN   8617984ull   // 32*2048
#define OFF_CHA  8683520ull   // 32*8385
#define OFF_CHS  8951840ull   // 32*8385
#define OFF_VS   9220160ull   // 32*2048*64 -> end 13414464 floats (53.7 MB)

__device__ inline unsigned long long pack_key(float v, int idx) {
    unsigned u = __float_as_uint(v);
    u = (u & 0x80000000u) ? ~u : (u | 0x80000000u);
    return ((unsigned long long)u << 32) | (unsigned)idx;
}
__device__ inline float unpack_key(unsigned long long k) {
    unsigned u = (unsigned)(k >> 32);
    u = (u & 0x80000000u) ? (u ^ 0x80000000u) : ~u;
    return __uint_as_float(u);
}
__device__ inline unsigned long long shfl_xor_u64(unsigned long long x, int mask) {
    unsigned lo = (unsigned)x, hi = (unsigned)(x >> 32);
    lo = (unsigned)__shfl_xor((int)lo, mask, 64);
    hi = (unsigned)__shfl_xor((int)hi, mask, 64);
    return ((unsigned long long)hi << 32) | lo;
}

// ---------------- GEMM 1 + fused s1/s2 projection ----------------
__global__ __launch_bounds__(256) void gemm1_k(const float* __restrict__ X,
                                               const float* __restrict__ Wh,
                                               const float* __restrict__ aH,
                                               float* __restrict__ hh,
                                               float* __restrict__ s1h,
                                               float* __restrict__ s2h) {
    __shared__ float As[64][68];
    __shared__ float Bs[64][68];
    const int tid = threadIdx.x;
    const int bm = blockIdx.x, h = blockIdx.y;
    const int c0 = tid & 63, r0 = tid >> 6;
#pragma unroll
    for (int r = 0; r < 16; ++r) {
        int row = r0 + r * 4;
        As[c0][row] = X[(size_t)(bm * 64 + row) * 64 + c0];
        Bs[row][c0] = Wh[h * 4096 + row * 64 + c0];
    }
    __syncthreads();
    const int tx = tid & 15, ty = tid >> 4;
    const int m0 = ty * 4, n0 = tx * 4;
    float acc[4][4] = {};
#pragma unroll
    for (int kk = 0; kk < 64; ++kk) {
        float4 a = *(const float4*)&As[kk][m0];
        float4 b = *(const float4*)&Bs[kk][n0];
        acc[0][0] += a.x * b.x; acc[0][1] += a.x * b.y; acc[0][2] += a.x * b.z; acc[0][3] += a.x * b.w;
        acc[1][0] += a.y * b.x; acc[1][1] += a.y * b.y; acc[1][2] += a.y * b.z; acc[1][3] += a.y * b.w;
        acc[2][0] += a.z * b.x; acc[2][1] += a.z * b.y; acc[2][2] += a.z * b.z; acc[2][3] += a.z * b.w;
        acc[3][0] += a.w * b.x; acc[3][1] += a.w * b.y; acc[3][2] += a.w * b.z; acc[3][3] += a.w * b.w;
    }
#pragma unroll
    for (int i = 0; i < 4; ++i) {
        float4 v = make_float4(acc[i][0], acc[i][1], acc[i][2], acc[i][3]);
        *(float4*)&hh[(size_t)(bm * 64 + m0 + i) * 256 + h * 64 + n0] = v;
    }
#pragma unroll
    for (int i = 0; i < 4; ++i) {
        float p1 = 0.f, p2 = 0.f;
#pragma unroll
        for (int jj = 0; jj < 4; ++jj) {
            p1 += acc[i][jj] * aH[h * 128 + n0 + jj];
            p2 += acc[i][jj] * aH[h * 128 + 64 + n0 + jj];
        }
#pragma unroll
        for (int off = 8; off; off >>= 1) {
            p1 += __shfl_xor(p1, off, 16);
            p2 += __shfl_xor(p2, off, 16);
        }
        if (tx == 0) {
            s1h[h * NTOT + bm * 64 + m0 + i] = p1;
            s2h[h * NTOT + bm * 64 + m0 + i] = p2;
        }
    }
}

// ---------------- GEMM 2 + fused s1/s2 projection ----------------
__global__ __launch_bounds__(256) void gemm2_k(const float* __restrict__ XC,
                                               const float* __restrict__ Wo,
                                               const float* __restrict__ aO,
                                               float* __restrict__ hc,
                                               float* __restrict__ s1o,
                                               float* __restrict__ s2o) {
    __shared__ float As[64][68];
    __shared__ float Bs[64][68];
    const int tid = threadIdx.x;
    const int bm = blockIdx.x;
    const int c0 = tid & 63, r0 = tid >> 6;
    const int tx = tid & 15, ty = tid >> 4;
    const int m0 = ty * 4, n0 = tx * 4;
    float acc[4][4] = {};
    for (int kt = 0; kt < 4; ++kt) {
#pragma unroll
        for (int r = 0; r < 16; ++r) {
            int row = r0 + r * 4;
            As[c0][row] = XC[(size_t)(bm * 64 + row) * 256 + kt * 64 + c0];
            Bs[row][c0] = Wo[(kt * 64 + row) * 64 + c0];
        }
        __syncthreads();
#pragma unroll
        for (int kk = 0; kk < 64; ++kk) {
            float4 a = *(const float4*)&As[kk][m0];
            float4 b = *(const float4*)&Bs[kk][n0];
            acc[0][0] += a.x * b.x; acc[0][1] += a.x * b.y; acc[0][2] += a.x * b.z; acc[0][3] += a.x * b.w;
            acc[1][0] += a.y * b.x; acc[1][1] += a.y * b.y; acc[1][2] += a.y * b.z; acc[1][3] += a.y * b.w;
            acc[2][0] += a.z * b.x; acc[2][1] += a.z * b.y; acc[2][2] += a.z * b.z; acc[2][3] += a.z * b.w;
            acc[3][0] += a.w * b.x; acc[3][1] += a.w * b.y; acc[3][2] += a.w * b.z; acc[3][3] += a.w * b.w;
        }
        __syncthreads();
    }
#pragma unroll
    for (int i = 0; i < 4; ++i) {
        float4 v = make_float4(acc[i][0], acc[i][1], acc[i][2], acc[i][3]);
        *(float4*)&hc[(size_t)(bm * 64 + m0 + i) * 64 + n0] = v;
    }
#pragma unroll
    for (int i = 0; i < 4; ++i) {
        float p1 = 0.f, p2 = 0.f;
#pragma unroll
        for (int jj = 0; jj < 4; ++jj) {
            p1 += acc[i][jj] * aO[n0 + jj];
            p2 += acc[i][jj] * aO[64 + n0 + jj];
        }
#pragma unroll
        for (int off = 8; off; off >>= 1) {
            p1 += __shfl_xor(p1, off, 16);
            p2 += __shfl_xor(p2, off, 16);
        }
        if (tx == 0) {
            s1o[bm * 64 + m0 + i] = p1;
            s2o[bm * 64 + m0 + i] = p2;
        }
    }
}

// ---- fused: bitonic sort + V reorder + chunk sums + parallel chunk scans; 1 block/task ----
__global__ __launch_bounds__(1024) void sortchunkscan_k(const float* __restrict__ s2_all,
                                                        const float* __restrict__ V,
                                                        int heads, int vstride,
                                                        float* __restrict__ g_sval,
                                                        float* __restrict__ g_wN,
                                                        float* __restrict__ g_chA, float* __restrict__ g_chS,
                                                        float* __restrict__ g_Vs) {
    __shared__ unsigned long long sA[1024];
    __shared__ unsigned long long sB[1024];
    __shared__ float chA[8320];
    __shared__ float chS[8320];
    __shared__ float swn[NSEG];
    __shared__ int ssi[NSEG];
    __shared__ float btA[4][65];
    __shared__ float btS[4][65];
    __shared__ float sM2;
    const int tid = threadIdx.x, t = blockIdx.x;
    const int g = t / heads, h = t % heads;
    const float* s2p = s2_all + (size_t)h * NTOT + (size_t)g * NSEG;
    const float* Vp = V + (size_t)g * NSEG * vstride + h * 64;
    float* Vst = g_Vs + (size_t)t * NSEG * 64;

    unsigned long long a0 = pack_key(s2p[tid], tid);
    unsigned long long a1 = pack_key(s2p[tid + 1024], tid + 1024);
    for (int k = 2; k <= 2048; k <<= 1) {
        const bool up0 = (tid & k) == 0;
        const bool up1 = (((tid + 1024) & k) == 0);
        for (int j = k >> 1; j > 0; j >>= 1) {
            if (j >= 1024) {
                unsigned long long lo = a0 < a1 ? a0 : a1;
                unsigned long long hi = a0 < a1 ? a1 : a0;
                a0 = up0 ? lo : hi;
                a1 = up0 ? hi : lo;
            } else if (j >= 64) {
                __syncthreads();
                sA[tid] = a0; sB[tid] = a1;
                __syncthreads();
                unsigned long long p0 = sA[tid ^ j], p1 = sB[tid ^ j];
                bool lower = (tid & j) == 0;
                a0 = ((a0 < p0) == (lower == up0)) ? a0 : p0;
                a1 = ((a1 < p1) == (lower == up1)) ? a1 : p1;
            } else {
                unsigned long long p0 = shfl_xor_u64(a0, j);
                unsigned long long p1 = shfl_xor_u64(a1, j);
                bool lower = (tid & j) == 0;
                a0 = ((a0 < p0) == (lower == up0)) ? a0 : p0;
                a1 = ((a1 < p1) == (lower == up1)) ? a1 : p1;
            }
        }
    }
    float v0 = unpack_key(a0), v1 = unpack_key(a1);
    if (tid == 1023) sM2 = v1;
    __syncthreads();
    const float M2 = sM2;
    int i0 = (int)(unsigned)(a0 & 0xffffffffu);
    int i1 = (int)(unsigned)(a1 & 0xffffffffu);
    float w0 = __expf(0.2f * (v0 - M2));
    float w1 = __expf(0.2f * (v1 - M2));
    size_t o = (size_t)t * NSEG;
    g_sval[o + tid] = v0; g_sval[o + tid + 1024] = v1;
    g_wN[o + tid] = w0;   g_wN[o + tid + 1024] = w1;
    swn[tid] = w0; swn[tid + 1024] = w1;
    ssi[tid] = i0; ssi[tid + 1024] = i1;
    __syncthreads();
    // chunk sums + sorted-V write: wave wv handles chunks 8*wv..8*wv+7; lane = dim
    const int wv = tid >> 6, lane = tid & 63;
    for (int cc = 0; cc < 8; ++cc) {
        int c = wv * 8 + cc, base = c * 16;
        float sa = 0.f, swa = 0.f, ss = 0.f, sws = 0.f;
#pragma unroll
        for (int j = 0; j < 16; ++j) {
            float wn = swn[base + j];
            int row = ssi[base + j];
            float v = Vp[(size_t)row * vstride + lane];
            Vst[(size_t)(base + j) * 64 + lane] = v;
            float w2 = wn * wn, wp = w2 * w2 * wn;
            sa += wn * v; swa += wn;
            ss += wp * v; sws += wp;
        }
        chA[c * 65 + lane] = sa; chS[c * 65 + lane] = ss;
        if (lane == 0) { chA[c * 65 + 64] = swa; chS[c * 65 + 64] = sws; }
    }
    __syncthreads();
    // phase 1: per-column scans within 4 groups of 32 chunks (A prefix / S suffix, disjoint threads)
    if (tid < 260) {
        int b = tid / 65, d = tid % 65;
        float run = 0.f;
        for (int c = b * 32; c < b * 32 + 32; ++c) { float v = chA[c * 65 + d]; chA[c * 65 + d] = run; run += v; }
        btA[b][d] = run;
    } else if (tid >= 512 && tid < 772) {
        int u = tid - 512;
        int b = u / 65, d = u % 65;
        float run = 0.f;
        for (int c = b * 32 + 31; c >= b * 32; --c) { run += chS[c * 65 + d]; chS[c * 65 + d] = run; }
        btS[b][d] = run;
    }
    __syncthreads();
    // phase 2: scan the 4 group totals; write boundary rows (row 128)
    if (tid < 65) {
        float run = 0.f;
        for (int b = 0; b < 4; ++b) { float v = btA[b][tid]; btA[b][tid] = run; run += v; }
        g_chA[(size_t)t * CROWS + 8320 + tid] = run;   // row 128: total (k=2048)
    } else if (tid >= 512 && tid < 577) {
        int d = tid - 512;
        float run = 0.f;
        for (int b = 3; b >= 0; --b) { float v = btS[b][d]; btS[b][d] = run; run += v; }
        g_chS[(size_t)t * CROWS + 8320 + d] = 0.f;     // row 128: empty suffix
    }
    __syncthreads();
    // phase 3: add group offsets
    if (tid < 512) {
        for (int i = tid; i < 8320; i += 512) chA[i] += btA[(i / 65) >> 5][i % 65];
    } else {
        for (int i = tid - 512; i < 8320; i += 512) chS[i] += btS[(i / 65) >> 5][i % 65];
    }
    __syncthreads();
    for (int i = tid; i < 8320; i += 1024) {
        g_chA[(size_t)t * CROWS + i] = chA[i];
        g_chS[(size_t)t * CROWS + i] = chS[i];
    }
}

// ---- query: binary search + chunk rows + 16-contiguous-row walk; 16 queries/wave ----
template <int MODE>  // 0: ELU -> xc ; 1: ELU + log_softmax -> out
__global__ __launch_bounds__(256) void seg_query_k(const float* __restrict__ s1_all,
                                                   float* __restrict__ out,
                                                   int heads, int ostride,
                                                   const float* __restrict__ g_sval,
                                                   const float* __restrict__ g_wN,
                                                   const float* __restrict__ g_chA,
                                                   const float* __restrict__ g_chS,
                                                   const float* __restrict__ g_Vs) {
    __shared__ float sval[NSEG];
    __shared__ float swn[NSEG];
    const int tid = threadIdx.x;
    const int t = blockIdx.y, g = t / heads, h = t % heads;
    const float4* sv4 = (const float4*)(g_sval + (size_t)t * NSEG);
    const float4* wn4 = (const float4*)(g_wN + (size_t)t * NSEG);
    for (int i = tid; i < NSEG / 4; i += 256) {
        ((float4*)sval)[i] = sv4[i];
        ((float4*)swn)[i] = wn4[i];
    }
    __syncthreads();
    const float M2 = sval[NSEG - 1];
    const int lane = tid & 63, wv = tid >> 6;
    const int q0 = blockIdx.x * 64 + wv * 16;
    const float* s1p = s1_all + (size_t)h * NTOT + (size_t)g * NSEG;
    float* outp = out + (size_t)g * NSEG * ostride + h * 64;
    const float* cAg = g_chA + (size_t)t * CROWS;
    const float* cSg = g_chS + (size_t)t * CROWS;
    const float* Vst = g_Vs + (size_t)t * NSEG * 64;
    int myq = q0 + (lane & 15);
    float s1v = s1p[myq];
    float th = -s1v;
    int lo = 0, hi = NSEG;
    while (lo < hi) { int mid = (lo + hi) >> 1; if (sval[mid] <= th) lo = mid + 1; else hi = mid; }
    for (int j = 0; j < 16; ++j) {
        int k = __shfl(lo, j, 64);
        float s1q = __shfl(s1v, j, 64);
        int ck = k >> 4; if (ck > 127) ck = 127;
        const float* rA = cAg + ck * 65;
        const float* rS = cSg + (ck + 1) * 65;
        float accA = rA[lane], scaA = rA[64];
        float accS = rS[lane], scaS = rS[64];
        int base = ck * 16;
#pragma unroll
        for (int jj = 0; jj < 16; ++jj) {
            int pos = base + jj;
            float v = Vst[(size_t)pos * 64 + lane];
            float wn = swn[pos];
            float w2 = wn * wn, wp = w2 * w2 * wn;
            bool isA = pos < k;
            accA += isA ? wn * v : 0.f; scaA += isA ? wn : 0.f;
            accS += isA ? 0.f : wp * v; scaS += isA ? 0.f : wp;
        }
        float cc = __expf(-0.8f * fmaxf(s1q + M2, 0.f));
        float o = (accS + cc * accA) / (scaS + cc * scaA);
        o = o > 0.f ? o : expm1f(o);  // ELU
        int q = q0 + j;
        if (MODE == 0) {
            outp[(size_t)q * ostride + lane] = o;
        } else {
            float m = o;
#pragma unroll
            for (int off = 32; off; off >>= 1) m = fmaxf(m, __shfl_xor(m, off, 64));
            float e = __expf(o - m);
#pragma unroll
            for (int off = 32; off; off >>= 1) e += __shfl_xor(e, off, 64);
            outp[(size_t)q * ostride + lane] = o - m - __logf(e);
        }
    }
}

extern "C" void kernel_launch(void* const* d_in, const int* in_sizes, int n_in,
                              void* d_out, int out_size, void* d_ws, size_t ws_size,
                              hipStream_t stream) {
    const float* h_states = (const float*)d_in[0];
    const float* W_heads = (const float*)d_in[1];
    const float* a_heads = (const float*)d_in[2];
    const float* W_out = (const float*)d_in[3];
    const float* a_out = (const float*)d_in[4];
    float* w = (float*)d_ws;
    float* hh = w + OFF_HH;
    float* xc = w + OFF_XC;
    float* hc = w + OFF_HH;  // reuse: hh dead after head-layer sortchunkscan (V copied to Vs)
    float* s1h = w + OFF_S1H;
    float* s2h = w + OFF_S2H;
    float* s1o = w + OFF_S1O;
    float* s2o = w + OFF_S2O;
    float* g_sval = w + OFF_SVAL;
    float* g_wN = w + OFF_WN;
    float* g_chA = w + OFF_CHA;
    float* g_chS = w + OFF_CHS;
    float* g_Vs = w + OFF_VS;
    float* outp = (float*)d_out;

    gemm1_k<<<dim3(256, 4), 256, 0, stream>>>(h_states, W_heads, a_heads, hh, s1h, s2h);
    sortchunkscan_k<<<32, 1024, 0, stream>>>(s2h, hh, 4, 256, g_sval, g_wN, g_chA, g_chS, g_Vs);
    seg_query_k<0><<<dim3(32, 32), 256, 0, stream>>>(s1h, xc, 4, 256, g_sval, g_wN, g_chA, g_chS, g_Vs);
    gemm2_k<<<256, 256, 0, stream>>>(xc, W_out, a_out, hc, s1o, s2o);
    sortchunkscan_k<<<8, 1024, 0, stream>>>(s2o, hc, 1, 64, g_sval, g_wN, g_chA, g_chS, g_Vs);
    seg_query_k<1><<<dim3(32, 8), 256, 0, stream>>>(s1o, outp, 1, 64, g_sval, g_wN, g_chA, g_chS, g_Vs);
}